// Round 18
// baseline (159.448 us; speedup 1.0000x reference)
//
#include <hip/hip_runtime.h>

#define NN 100000      // nodes
#define DD 128         // embedding dim
#define KE 300         // raw feature dim
#define NE 1600000     // edges
#define NB 4096        // batch (users)
#define HL 50          // history length
#define CL 20          // candidates

#define NBUCK 1563     // ceil(NN/64): buckets of 64 dst nodes
#define SLOT  1280     // max edges/bucket (mean 1024, sigma 32, +8 sigma)
#define PBLK  250      // partition blocks
#define EPB   6400     // edges per partition block
#define EPT   25       // edges per thread
#define EBLK  1563     // enc row-tiles (64 rows each)
#define ENCB  512      // persistent enc blocks (2 per CU)

#define WTE_N 40960    // 128 cols x 320 k, fragment-major
#define WTG_N 16384    // 128 cols x 128 k, fragment-major
#define PREPB ((WTE_N + WTG_N + 255) / 256)   // 224 weight-prep blocks

typedef unsigned short ushort_t;
typedef unsigned char uchar_t;
using bf16x8 = __attribute__((ext_vector_type(8))) short;
using f32x4  = __attribute__((ext_vector_type(4))) float;
using v2f    = __attribute__((ext_vector_type(2))) float;

union U4B { uint4 u; bf16x8 b; unsigned a[4]; };

__device__ __forceinline__ ushort_t f2bf(float f) {
    unsigned u = __float_as_uint(f);
    unsigned r = u + 0x7FFF + ((u >> 16) & 1);   // RNE
    return (ushort_t)(r >> 16);
}
__device__ __forceinline__ float bf2f(unsigned s) {
    return __uint_as_float(s << 16);
}
__device__ __forceinline__ bf16x8 pack8(float4 a, float4 b) {
    U4B r;
    r.a[0] = (unsigned)f2bf(a.x) | ((unsigned)f2bf(a.y) << 16);
    r.a[1] = (unsigned)f2bf(a.z) | ((unsigned)f2bf(a.w) << 16);
    r.a[2] = (unsigned)f2bf(b.x) | ((unsigned)f2bf(b.y) << 16);
    r.a[3] = (unsigned)f2bf(b.z) | ((unsigned)f2bf(b.w) << 16);
    return r.b;
}

// ---- masked A fragment loader (tail chunk crossing KE) ---------------------
__device__ __forceinline__ bf16x8 loadA8m(const float* __restrict__ x,
                                          int row, int col, bool rowok) {
    float v[8];
#pragma unroll
    for (int j = 0; j < 8; ++j) {
        int c = col + j;
        v[j] = (rowok && c < KE) ? x[(long long)row * KE + c] : 0.f;
    }
    return pack8(make_float4(v[0], v[1], v[2], v[3]),
                 make_float4(v[4], v[5], v[6], v[7]));
}

// ------- fused prep: edge partition (blocks < PBLK) + weight transpose ------
// wtF[((chunk*8+cf)*64 + lane)*8 + j] = W[k][n],
//   k = chunk*32 + (lane>>4)*8 + j,  n = cf*16 + (lane&15).
__global__ __launch_bounds__(256) void k_prep(const int* __restrict__ ei,
                                              unsigned* __restrict__ gcur,
                                              unsigned* __restrict__ pairs,
                                              const float* __restrict__ We,
                                              const float* __restrict__ Wg,
                                              ushort_t* __restrict__ wte,
                                              ushort_t* __restrict__ wtg) {
    __shared__ unsigned sh[NBUCK], sb[NBUCK], sc[NBUCK];
    const int tid = threadIdx.x;

    if (blockIdx.x < PBLK) {
        const int eb = blockIdx.x * EPB;
        for (int i = tid; i < NBUCK; i += 256) sh[i] = 0;
        __syncthreads();

        unsigned val[EPT], bk[EPT];
#pragma unroll
        for (int l = 0; l < EPT; ++l) {
            int e = eb + l * 256 + tid;
            unsigned src = (unsigned)ei[e];
            unsigned dst = (unsigned)ei[NE + e];
            val[l] = (src << 6) | (dst & 63u);
            bk[l] = dst >> 6;
            atomicAdd(&sh[bk[l]], 1u);
        }
        __syncthreads();

        for (int i = tid; i < NBUCK; i += 256) {
            unsigned h = sh[i];
            sb[i] = (unsigned)i * SLOT + (h ? atomicAdd(&gcur[i], h) : 0u);
            sc[i] = 0;
        }
        __syncthreads();

#pragma unroll
        for (int l = 0; l < EPT; ++l) {
            unsigned b = bk[l];
            unsigned pos = sb[b] + atomicAdd(&sc[b], 1u);
            if (pos < (b + 1u) * SLOT) pairs[pos] = val[l];   // overflow guard
        }
        return;
    }

    int i = (blockIdx.x - PBLK) * 256 + tid;
    if (i < WTE_N) {
        int j = i & 7, lane = (i >> 3) & 63, cf = (i >> 9) & 7, ch = i >> 12;
        int k = ch * 32 + (lane >> 4) * 8 + j;
        int n = cf * 16 + (lane & 15);
        wte[i] = f2bf((k < KE) ? We[k * DD + n] : 0.f);
    } else if (i < WTE_N + WTG_N) {
        int t = i - WTE_N;
        int j = t & 7, lane = (t >> 3) & 63, cf = (t >> 9) & 7, ks = t >> 12;
        int k = ks * 32 + (lane >> 4) * 8 + j;
        int n = cf * 16 + (lane & 15);
        wtg[t] = f2bf(Wg[k * DD + n]);
    }
}

// ---------------- encoder: weights-stationary persistent GEMM ---------------
// All 80 B fragments resident in VGPRs; A loaded in TWO pipelined halves so
// peak register liveness stays under 256 (B160 + acc32 + A0 20 + ra1 36).
// No LDS, no barriers. fp8 sidecar produced by separate k_cvt8.
__global__ __launch_bounds__(256, 1) void enc_mfma(const float* __restrict__ x,
                                                   const ushort_t* __restrict__ wtF,
                                                   ushort_t* __restrict__ news) {
    const int tid = threadIdx.x;
    const int w = tid >> 6, lane = tid & 63;
    const int hl = lane & 15, kg = lane >> 4;

    bf16x8 B[10][8];
#pragma unroll
    for (int c = 0; c < 10; ++c)
#pragma unroll
        for (int cf = 0; cf < 8; ++cf)
            B[c][cf] = *(const bf16x8*)&wtF[(c * 8 + cf) * 512 + lane * 8];

    for (int tile = blockIdx.x; tile < EBLK; tile += gridDim.x) {
        const int row0 = tile * 64 + w * 16;
        const int r0 = row0 + hl;
        const bool ok0 = r0 < NN;
        const float* xr = &x[(long long)r0 * KE + kg * 8];
        const float4 fz = make_float4(0.f, 0.f, 0.f, 0.f);

        // ---- half 1: chunks 0..4 raw loads (10 float4, independent) ----
        float4 ra0[5][2];
        if (ok0) {
#pragma unroll
            for (int c = 0; c < 5; ++c) {
                const float4* p = (const float4*)(xr + c * 32);
                ra0[c][0] = p[0];
                ra0[c][1] = p[1];
            }
        } else {
#pragma unroll
            for (int c = 0; c < 5; ++c) { ra0[c][0] = fz; ra0[c][1] = fz; }
        }
        // pack half 1 (raws die -> frees 40 regs)
        bf16x8 A0[5];
#pragma unroll
        for (int c = 0; c < 5; ++c) A0[c] = pack8(ra0[c][0], ra0[c][1]);

        // ---- half 2: issue chunks 5..8 raw + masked chunk 9 ----
        float4 ra1[4][2];
        if (ok0) {
#pragma unroll
            for (int c = 0; c < 4; ++c) {
                const float4* p = (const float4*)(xr + (5 + c) * 32);
                ra1[c][0] = p[0];
                ra1[c][1] = p[1];
            }
        } else {
#pragma unroll
            for (int c = 0; c < 4; ++c) { ra1[c][0] = fz; ra1[c][1] = fz; }
        }
        bf16x8 a9 = loadA8m(x, r0, 288 + kg * 8, ok0);

        f32x4 acc[8];
#pragma unroll
        for (int j = 0; j < 8; ++j) acc[j] = (f32x4)0.f;

        // ---- MFMA half 1 (overlaps half-2 HBM latency) ----
#pragma unroll
        for (int c = 0; c < 5; ++c)
#pragma unroll
            for (int cf = 0; cf < 8; ++cf)
                acc[cf] = __builtin_amdgcn_mfma_f32_16x16x32_bf16(A0[c], B[c][cf], acc[cf], 0, 0, 0);

        // ---- pack + MFMA half 2 ----
#pragma unroll
        for (int c = 0; c < 4; ++c) {
            bf16x8 a = pack8(ra1[c][0], ra1[c][1]);
#pragma unroll
            for (int cf = 0; cf < 8; ++cf)
                acc[cf] = __builtin_amdgcn_mfma_f32_16x16x32_bf16(a, B[5 + c][cf], acc[cf], 0, 0, 0);
        }
#pragma unroll
        for (int cf = 0; cf < 8; ++cf)
            acc[cf] = __builtin_amdgcn_mfma_f32_16x16x32_bf16(a9, B[9][cf], acc[cf], 0, 0, 0);

#pragma unroll
        for (int cf = 0; cf < 8; ++cf)
#pragma unroll
            for (int j = 0; j < 4; ++j) {
                int grow = row0 + kg * 4 + j;
                int gcol = cf * 16 + hl;
                if (grow < NN)
                    news[(long long)grow * DD + gcol] = f2bf(acc[cf][j]);
            }
    }
}

// ---------------- bf16 -> fp8 e4m3 sidecar (coalesced, separate pass) -------
__global__ __launch_bounds__(256) void k_cvt8(const ushort_t* __restrict__ nb,
                                              uchar_t* __restrict__ n8) {
    long long i = (long long)blockIdx.x * 256 + threadIdx.x;
    uint4 v = *(const uint4*)&nb[i * 8];
    float f[8];
    f[0] = bf2f(v.x & 0xFFFFu); f[1] = bf2f(v.x >> 16);
    f[2] = bf2f(v.y & 0xFFFFu); f[3] = bf2f(v.y >> 16);
    f[4] = bf2f(v.z & 0xFFFFu); f[5] = bf2f(v.z >> 16);
    f[6] = bf2f(v.w & 0xFFFFu); f[7] = bf2f(v.w >> 16);
    int p0 = __builtin_amdgcn_cvt_pk_fp8_f32(f[0], f[1], 0, false);
    p0     = __builtin_amdgcn_cvt_pk_fp8_f32(f[2], f[3], p0, true);
    int p1 = __builtin_amdgcn_cvt_pk_fp8_f32(f[4], f[5], 0, false);
    p1     = __builtin_amdgcn_cvt_pk_fp8_f32(f[6], f[7], p1, true);
    *(uint2*)&n8[i * 8] = make_uint2((unsigned)p0, (unsigned)p1);
}

// ------- fused bucket aggregate + GNN GEMM + epilogue (512 threads) ---------
// Phase A: 64-dst LDS CSR + fp8 register gather (128B rows, half the bytes);
// agg rows in LDS (bf16, chunk-XOR swizzle). Phase B: 8 waves = 4 row-groups
// x 2 cf-halves MFMA + residual (bf16 news). xx output bf16.
__global__ __launch_bounds__(512) void k_baggnn(const unsigned* __restrict__ gcur,
                                                const unsigned* __restrict__ pairs,
                                                const uchar_t* __restrict__ nf8,
                                                const ushort_t* __restrict__ news,
                                                const ushort_t* __restrict__ wtF,
                                                ushort_t* __restrict__ xxb) {
    __shared__ unsigned srcs[SLOT];
    __shared__ unsigned hist[64], base[64], cur[64];
    __shared__ ushort_t aggs[64 * DD];         // 16 KB, swizzled 16B chunks
    const int tid = threadIdx.x;
    const int b = blockIdx.x;
    int cnt = (int)gcur[b];
    if (cnt > SLOT) cnt = SLOT;

    if (tid < 64) hist[tid] = 0;
    __syncthreads();
    for (int i = tid; i < cnt; i += 512)
        atomicAdd(&hist[pairs[b * SLOT + i] & 63u], 1u);
    __syncthreads();

    // single-wave exclusive scan of 64 bins
    if (tid < 64) {
        unsigned h = hist[tid], v = h;
#pragma unroll
        for (int off = 1; off < 64; off <<= 1) {
            unsigned n = __shfl_up(v, off);
            if (tid >= off) v += n;
        }
        base[tid] = v - h;
        cur[tid]  = v - h;
    }
    __syncthreads();

    for (int i = tid; i < cnt; i += 512) {
        unsigned v = pairs[b * SLOT + i];
        srcs[atomicAdd(&cur[v & 63u], 1u)] = v >> 6;
    }
    __syncthreads();

    // ---- phase A: wave per dst (8 waves), 4 edge slots x 16 chunk lanes,
    //      8B fp8 per lane, depth-2 pipeline ----
    const int w = tid >> 6, lane = tid & 63;
    const int e = lane >> 4, l = lane & 15;
    for (int d = w; d < 64; d += 8) {
        int gd = b * 64 + d;
        if (gd >= NN) break;                 // uniform per wave
        int s0 = (int)base[d], c = (int)hist[d];
        float acc[8];
#pragma unroll
        for (int j = 0; j < 8; ++j) acc[j] = 0.f;

        uint2 v = make_uint2(0u, 0u);
        if (e < c)
            v = *(const uint2*)&nf8[(long long)srcs[s0 + e] * DD + l * 8];
        for (int i = 4; i < c; i += 4) {
            uint2 vn = make_uint2(0u, 0u);
            int ii = i + e;
            if (ii < c)
                vn = *(const uint2*)&nf8[(long long)srcs[s0 + ii] * DD + l * 8];
            v2f d0 = __builtin_amdgcn_cvt_pk_f32_fp8((int)v.x, false);
            v2f d1 = __builtin_amdgcn_cvt_pk_f32_fp8((int)v.x, true);
            acc[0] += d0[0]; acc[1] += d0[1]; acc[2] += d1[0]; acc[3] += d1[1];
            d0 = __builtin_amdgcn_cvt_pk_f32_fp8((int)v.y, false);
            d1 = __builtin_amdgcn_cvt_pk_f32_fp8((int)v.y, true);
            acc[4] += d0[0]; acc[5] += d0[1]; acc[6] += d1[0]; acc[7] += d1[1];
            v = vn;
        }
        {
            v2f d0 = __builtin_amdgcn_cvt_pk_f32_fp8((int)v.x, false);
            v2f d1 = __builtin_amdgcn_cvt_pk_f32_fp8((int)v.x, true);
            acc[0] += d0[0]; acc[1] += d0[1]; acc[2] += d1[0]; acc[3] += d1[1];
            d0 = __builtin_amdgcn_cvt_pk_f32_fp8((int)v.y, false);
            d1 = __builtin_amdgcn_cvt_pk_f32_fp8((int)v.y, true);
            acc[4] += d0[0]; acc[5] += d0[1]; acc[6] += d1[0]; acc[7] += d1[1];
        }

#pragma unroll
        for (int j = 0; j < 8; ++j) {
            acc[j] += __shfl_xor(acc[j], 16);
            acc[j] += __shfl_xor(acc[j], 32);
        }
        if (e == 0) {
            uint4 o;
            o.x = (unsigned)f2bf(acc[0]) | ((unsigned)f2bf(acc[1]) << 16);
            o.y = (unsigned)f2bf(acc[2]) | ((unsigned)f2bf(acc[3]) << 16);
            o.z = (unsigned)f2bf(acc[4]) | ((unsigned)f2bf(acc[5]) << 16);
            o.w = (unsigned)f2bf(acc[6]) | ((unsigned)f2bf(acc[7]) << 16);
            *(uint4*)&aggs[d * DD + (l ^ (d & 15)) * 8] = o;   // swizzled chunk
        }
    }
    __syncthreads();

    // ---- phase B: gnn MFMA; wave w -> rows (w&3)*16, cf half (w>>2)*4 ----
    const int hl = lane & 15, kg = lane >> 4;
    const int rw = (w & 3) * 16;
    const int cfb = (w >> 2) * 4;
    U4B a[4];
#pragma unroll
    for (int ks = 0; ks < 4; ++ks)
        a[ks].u = *(const uint4*)&aggs[(rw + hl) * DD + ((ks * 4 + kg) ^ hl) * 8];

    f32x4 acc[4];
#pragma unroll
    for (int j = 0; j < 4; ++j) acc[j] = (f32x4)0.f;

#pragma unroll
    for (int ks = 0; ks < 4; ++ks) {
        const ushort_t* bp = &wtF[(ks * 8 + cfb) * 512 + lane * 8];
#pragma unroll
        for (int cf = 0; cf < 4; ++cf) {
            bf16x8 bfr = *(const bf16x8*)&bp[cf * 512];
            acc[cf] = __builtin_amdgcn_mfma_f32_16x16x32_bf16(a[ks].b, bfr, acc[cf], 0, 0, 0);
        }
    }

#pragma unroll
    for (int j = 0; j < 4; ++j) {
        int lr = rw + kg * 4 + j;
        int grow = b * 64 + lr;
        if (grow < NN) {
            float s = 1.f / fmaxf((float)hist[lr], 1.f);
#pragma unroll
            for (int cf = 0; cf < 4; ++cf) {
                int gcol = (cfb + cf) * 16 + hl;
                float nv = bf2f((unsigned)news[(long long)grow * DD + gcol]);
                xxb[(long long)grow * DD + gcol] = f2bf(nv + acc[cf][j] * s);
            }
        }
    }
}

// ---------------- fused user vector + scores (bf16 xx gathers) --------------
__global__ __launch_bounds__(128) void k_user(const int* __restrict__ hist,
                                              const int* __restrict__ cand,
                                              const ushort_t* __restrict__ xxb,
                                              float* __restrict__ out) {
    __shared__ float part[2][128];
    __shared__ float cnts[2];
    __shared__ float uvs[128];
    const int b = blockIdx.x, t = threadIdx.x;
    const int w = t >> 6, lane = t & 63;

    float s0 = 0.f, s1 = 0.f, cnt = 0.f;
    for (int h = w; h < HL; h += 2) {
        int id = hist[b * HL + h];
        if (id != 0) {
            unsigned v = *(const unsigned*)&xxb[(long long)id * DD + lane * 2];
            s0 += bf2f(v & 0xFFFFu);
            s1 += bf2f(v >> 16);
            cnt += 1.f;
        }
    }
    part[w][lane * 2]     = s0;
    part[w][lane * 2 + 1] = s1;
    if (lane == 0) cnts[w] = cnt;
    __syncthreads();

    float inv = 1.f / fmaxf(cnts[0] + cnts[1], 1e-9f);
    uvs[t] = (part[0][t] + part[1][t]) * inv;
    __syncthreads();

    float2 uvp = *(const float2*)&uvs[lane * 2];
    for (int c = w; c < CL; c += 2) {
        int id = cand[b * CL + c];
        unsigned v = *(const unsigned*)&xxb[(long long)id * DD + lane * 2];
        float p = uvp.x * bf2f(v & 0xFFFFu) + uvp.y * bf2f(v >> 16);
#pragma unroll
        for (int off = 32; off >= 1; off >>= 1) p += __shfl_xor(p, off);
        if (lane == 0) out[b * CL + c] = p;
    }
}

extern "C" void kernel_launch(void* const* d_in, const int* in_sizes, int n_in,
                              void* d_out, int out_size, void* d_ws, size_t ws_size,
                              hipStream_t stream) {
    const float* x    = (const float*)d_in[0];
    // d_in[1] = n_id == arange(N) -> identity scatter, unused
    const int*   ei   = (const int*)d_in[2];
    const int*   hist = (const int*)d_in[3];
    const int*   cand = (const int*)d_in[4];
    const float* Wenc = (const float*)d_in[5];
    const float* Wgnn = (const float*)d_in[6];
    float* out = (float*)d_out;

    ushort_t* news_bf = (ushort_t*)d_ws;                   // [NN*DD] bf16
    ushort_t* xx_bf   = news_bf + (size_t)NN * DD;         // [NN*DD] bf16
    ushort_t* wt_enc  = xx_bf + (size_t)NN * DD;           // [WTE_N]
    ushort_t* wt_gnn  = wt_enc + WTE_N;                    // [WTG_N]
    uchar_t*  news_f8 = (uchar_t*)(wt_gnn + WTG_N);        // [NN*DD] fp8
    unsigned* gcur    = (unsigned*)(news_f8 + (size_t)NN * DD); // [NBUCK]
    unsigned* pairs   = gcur + NBUCK;                      // [NBUCK*SLOT]

    hipMemsetAsync(gcur, 0, NBUCK * sizeof(unsigned), stream);

    k_prep<<<PBLK + PREPB, 256, 0, stream>>>(ei, gcur, pairs, Wenc, Wgnn, wt_enc, wt_gnn);
    enc_mfma<<<ENCB, 256, 0, stream>>>(x, wt_enc, news_bf);
    k_cvt8<<<(NN * DD / 8 + 255) / 256, 256, 0, stream>>>(news_bf, news_f8);
    k_baggnn<<<NBUCK, 512, 0, stream>>>(gcur, pairs, news_f8, news_bf, wt_gnn, xx_bf);
    k_user<<<NB, 128, 0, stream>>>(hist, cand, xx_bf, out);
}

// Round 19
// 145.382 us; speedup vs baseline: 1.0968x; 1.0968x over previous
//
#include <hip/hip_runtime.h>

#define NN 100000      // nodes
#define DD 128         // embedding dim
#define KE 300         // raw feature dim
#define NE 1600000     // edges
#define NB 4096        // batch (users)
#define HL 50          // history length
#define CL 20          // candidates

#define NBUCK 1563     // ceil(NN/64): buckets of 64 dst nodes
#define SLOT  1280     // max edges/bucket (mean 1024, sigma 32, +8 sigma)
#define PBLK  250      // partition blocks (fused into enc dispatch)
#define EPB   6400     // edges per partition block
#define EPT   25       // edges per thread
#define EBLK  1563     // enc row-tiles (64 rows each)
#define ENCB  256      // persistent enc blocks

#define WTE_N 40960    // 128 cols x 320 k, fragment-major
#define WTG_N 16384    // 128 cols x 128 k, fragment-major
#define PREPB ((WTE_N + WTG_N + 255) / 256)   // 224 weight-prep blocks

typedef unsigned short ushort_t;
typedef unsigned char uchar_t;
using bf16x8 = __attribute__((ext_vector_type(8))) short;
using f32x4  = __attribute__((ext_vector_type(4))) float;
using v2f    = __attribute__((ext_vector_type(2))) float;

union U4B { uint4 u; bf16x8 b; unsigned a[4]; };

__device__ __forceinline__ ushort_t f2bf(float f) {
    unsigned u = __float_as_uint(f);
    unsigned r = u + 0x7FFF + ((u >> 16) & 1);   // RNE
    return (ushort_t)(r >> 16);
}
__device__ __forceinline__ float bf2f(unsigned s) {
    return __uint_as_float(s << 16);
}
__device__ __forceinline__ bf16x8 pack8(float4 a, float4 b) {
    U4B r;
    r.a[0] = (unsigned)f2bf(a.x) | ((unsigned)f2bf(a.y) << 16);
    r.a[1] = (unsigned)f2bf(a.z) | ((unsigned)f2bf(a.w) << 16);
    r.a[2] = (unsigned)f2bf(b.x) | ((unsigned)f2bf(b.y) << 16);
    r.a[3] = (unsigned)f2bf(b.z) | ((unsigned)f2bf(b.w) << 16);
    return r.b;
}

// ---- masked A fragment loader (tail chunk crossing KE) ---------------------
__device__ __forceinline__ bf16x8 loadA8m(const float* __restrict__ x,
                                          int row, int col, bool rowok) {
    float v[8];
#pragma unroll
    for (int j = 0; j < 8; ++j) {
        int c = col + j;
        v[j] = (rowok && c < KE) ? x[(long long)row * KE + c] : 0.f;
    }
    return pack8(make_float4(v[0], v[1], v[2], v[3]),
                 make_float4(v[4], v[5], v[6], v[7]));
}

// ------- weight prep (both matrices, fragment-major) ------------------------
// wtF[((chunk*8+cf)*64 + lane)*8 + j] = W[k][n],
//   k = chunk*32 + (lane>>4)*8 + j,  n = cf*16 + (lane&15).
__global__ __launch_bounds__(256) void k_wprep(const float* __restrict__ We,
                                               const float* __restrict__ Wg,
                                               ushort_t* __restrict__ wte,
                                               ushort_t* __restrict__ wtg) {
    int i = blockIdx.x * 256 + threadIdx.x;
    if (i < WTE_N) {
        int j = i & 7, lane = (i >> 3) & 63, cf = (i >> 9) & 7, ch = i >> 12;
        int k = ch * 32 + (lane >> 4) * 8 + j;
        int n = cf * 16 + (lane & 15);
        wte[i] = f2bf((k < KE) ? We[k * DD + n] : 0.f);
    } else if (i < WTE_N + WTG_N) {
        int t = i - WTE_N;
        int j = t & 7, lane = (t >> 3) & 63, cf = (t >> 9) & 7, ks = t >> 12;
        int k = ks * 32 + (lane >> 4) * 8 + j;
        int n = cf * 16 + (lane & 15);
        wtg[t] = f2bf(Wg[k * DD + n]);
    }
}

// ---- fused: edge partition (blocks < PBLK) + weights-stationary encoder ----
// Partition has no dependency on enc; co-resident blocks hide its ~13us under
// enc's runtime. Enc: all 80 B fragments resident in VGPRs, 10 independent A
// loads + 80 MFMAs per 64-row tile, bf16 news + LDS-staged fp8 sidecar.
__global__ __launch_bounds__(256, 1) void k_encpart(const float* __restrict__ x,
                                                    const ushort_t* __restrict__ wtF,
                                                    const int* __restrict__ ei,
                                                    unsigned* __restrict__ gcur,
                                                    unsigned* __restrict__ pairs,
                                                    ushort_t* __restrict__ news,
                                                    uchar_t* __restrict__ nf8) {
    __shared__ __align__(16) char smem[3 * NBUCK * 4];   // 18756 B, role-aliased
    const int tid = threadIdx.x;

    if (blockIdx.x < PBLK) {
        // ---------------- edge partition ----------------
        unsigned* sh = (unsigned*)smem;
        unsigned* sb = sh + NBUCK;
        unsigned* sc = sb + NBUCK;
        const int eb = blockIdx.x * EPB;
        for (int i = tid; i < NBUCK; i += 256) sh[i] = 0;
        __syncthreads();

        unsigned val[EPT], bk[EPT];
#pragma unroll
        for (int l = 0; l < EPT; ++l) {
            int e = eb + l * 256 + tid;
            unsigned src = (unsigned)ei[e];
            unsigned dst = (unsigned)ei[NE + e];
            val[l] = (src << 6) | (dst & 63u);
            bk[l] = dst >> 6;
            atomicAdd(&sh[bk[l]], 1u);
        }
        __syncthreads();

        for (int i = tid; i < NBUCK; i += 256) {
            unsigned h = sh[i];
            sb[i] = (unsigned)i * SLOT + (h ? atomicAdd(&gcur[i], h) : 0u);
            sc[i] = 0;
        }
        __syncthreads();

#pragma unroll
        for (int l = 0; l < EPT; ++l) {
            unsigned b = bk[l];
            unsigned pos = sb[b] + atomicAdd(&sc[b], 1u);
            if (pos < (b + 1u) * SLOT) pairs[pos] = val[l];   // overflow guard
        }
        return;
    }

    // ---------------- persistent encoder ----------------
    uchar_t* f8s = (uchar_t*)smem;             // 8 KB fp8 staging tile
    const int w = tid >> 6, lane = tid & 63;
    const int hl = lane & 15, kg = lane >> 4;

    bf16x8 B[10][8];
#pragma unroll
    for (int c = 0; c < 10; ++c)
#pragma unroll
        for (int cf = 0; cf < 8; ++cf)
            B[c][cf] = *(const bf16x8*)&wtF[(c * 8 + cf) * 512 + lane * 8];

    for (int tile = blockIdx.x - PBLK; tile < EBLK; tile += ENCB) {
        const int row0 = tile * 64 + w * 16;
        const int r0 = row0 + hl;
        const bool ok0 = r0 < NN;
        const float* xr = &x[(long long)r0 * KE + kg * 8];
        const float4 fz = make_float4(0.f, 0.f, 0.f, 0.f);

        float4 ra[9][2];
        if (ok0) {
#pragma unroll
            for (int c = 0; c < 9; ++c) {
                const float4* p = (const float4*)(xr + c * 32);
                ra[c][0] = p[0];
                ra[c][1] = p[1];
            }
        } else {
#pragma unroll
            for (int c = 0; c < 9; ++c) { ra[c][0] = fz; ra[c][1] = fz; }
        }
        bf16x8 a9 = loadA8m(x, r0, 288 + kg * 8, ok0);

        f32x4 acc[8];
#pragma unroll
        for (int j = 0; j < 8; ++j) acc[j] = (f32x4)0.f;

#pragma unroll
        for (int c = 0; c < 9; ++c) {
            bf16x8 a = pack8(ra[c][0], ra[c][1]);
#pragma unroll
            for (int cf = 0; cf < 8; ++cf)
                acc[cf] = __builtin_amdgcn_mfma_f32_16x16x32_bf16(a, B[c][cf], acc[cf], 0, 0, 0);
        }
#pragma unroll
        for (int cf = 0; cf < 8; ++cf)
            acc[cf] = __builtin_amdgcn_mfma_f32_16x16x32_bf16(a9, B[9][cf], acc[cf], 0, 0, 0);

        // bf16 main output + fp8 bytes into LDS staging
#pragma unroll
        for (int cf = 0; cf < 8; ++cf)
#pragma unroll
            for (int j = 0; j < 4; ++j) {
                int lr = w * 16 + kg * 4 + j;
                int grow = tile * 64 + lr;
                int gcol = cf * 16 + hl;
                if (grow < NN)
                    news[(long long)grow * DD + gcol] = f2bf(acc[cf][j]);
                int p = __builtin_amdgcn_cvt_pk_fp8_f32(acc[cf][j], 0.f, 0, false);
                f8s[lr * DD + gcol] = (uchar_t)(p & 0xFF);
            }
        __syncthreads();
        // coalesced fp8 copy: 32 B per thread
        {
            int r = tid >> 2, boff = (tid & 3) * 32;
            int grow = tile * 64 + r;
            if (grow < NN) {
                const uint4* s = (const uint4*)&f8s[r * DD + boff];
                uint4* d = (uint4*)&nf8[(long long)grow * DD + boff];
                d[0] = s[0];
                d[1] = s[1];
            }
        }
        __syncthreads();
    }
}

// ------- fused bucket aggregate + GNN GEMM + epilogue (512 threads) ---------
// Phase A: 64-dst LDS CSR + fp8 register gather (128B rows); agg rows in LDS
// (bf16, chunk-XOR swizzle). Phase B: 8 waves = 4 row-groups x 2 cf-halves
// MFMA + residual (bf16 news). xx output bf16.
__global__ __launch_bounds__(512) void k_baggnn(const unsigned* __restrict__ gcur,
                                                const unsigned* __restrict__ pairs,
                                                const uchar_t* __restrict__ nf8,
                                                const ushort_t* __restrict__ news,
                                                const ushort_t* __restrict__ wtF,
                                                ushort_t* __restrict__ xxb) {
    __shared__ unsigned srcs[SLOT];
    __shared__ unsigned hist[64], base[64], cur[64];
    __shared__ ushort_t aggs[64 * DD];         // 16 KB, swizzled 16B chunks
    const int tid = threadIdx.x;
    const int b = blockIdx.x;
    int cnt = (int)gcur[b];
    if (cnt > SLOT) cnt = SLOT;

    if (tid < 64) hist[tid] = 0;
    __syncthreads();
    for (int i = tid; i < cnt; i += 512)
        atomicAdd(&hist[pairs[b * SLOT + i] & 63u], 1u);
    __syncthreads();

    // single-wave exclusive scan of 64 bins
    if (tid < 64) {
        unsigned h = hist[tid], v = h;
#pragma unroll
        for (int off = 1; off < 64; off <<= 1) {
            unsigned n = __shfl_up(v, off);
            if (tid >= off) v += n;
        }
        base[tid] = v - h;
        cur[tid]  = v - h;
    }
    __syncthreads();

    for (int i = tid; i < cnt; i += 512) {
        unsigned v = pairs[b * SLOT + i];
        srcs[atomicAdd(&cur[v & 63u], 1u)] = v >> 6;
    }
    __syncthreads();

    // ---- phase A: wave per dst (8 waves), 4 edge slots x 16 chunk lanes,
    //      8B fp8 per lane, depth-2 pipeline ----
    const int w = tid >> 6, lane = tid & 63;
    const int e = lane >> 4, l = lane & 15;
    for (int d = w; d < 64; d += 8) {
        int gd = b * 64 + d;
        if (gd >= NN) break;                 // uniform per wave
        int s0 = (int)base[d], c = (int)hist[d];
        float acc[8];
#pragma unroll
        for (int j = 0; j < 8; ++j) acc[j] = 0.f;

        uint2 v = make_uint2(0u, 0u);
        if (e < c)
            v = *(const uint2*)&nf8[(long long)srcs[s0 + e] * DD + l * 8];
        for (int i = 4; i < c; i += 4) {
            uint2 vn = make_uint2(0u, 0u);
            int ii = i + e;
            if (ii < c)
                vn = *(const uint2*)&nf8[(long long)srcs[s0 + ii] * DD + l * 8];
            v2f d0 = __builtin_amdgcn_cvt_pk_f32_fp8((int)v.x, false);
            v2f d1 = __builtin_amdgcn_cvt_pk_f32_fp8((int)v.x, true);
            acc[0] += d0[0]; acc[1] += d0[1]; acc[2] += d1[0]; acc[3] += d1[1];
            d0 = __builtin_amdgcn_cvt_pk_f32_fp8((int)v.y, false);
            d1 = __builtin_amdgcn_cvt_pk_f32_fp8((int)v.y, true);
            acc[4] += d0[0]; acc[5] += d0[1]; acc[6] += d1[0]; acc[7] += d1[1];
            v = vn;
        }
        {
            v2f d0 = __builtin_amdgcn_cvt_pk_f32_fp8((int)v.x, false);
            v2f d1 = __builtin_amdgcn_cvt_pk_f32_fp8((int)v.x, true);
            acc[0] += d0[0]; acc[1] += d0[1]; acc[2] += d1[0]; acc[3] += d1[1];
            d0 = __builtin_amdgcn_cvt_pk_f32_fp8((int)v.y, false);
            d1 = __builtin_amdgcn_cvt_pk_f32_fp8((int)v.y, true);
            acc[4] += d0[0]; acc[5] += d0[1]; acc[6] += d1[0]; acc[7] += d1[1];
        }

#pragma unroll
        for (int j = 0; j < 8; ++j) {
            acc[j] += __shfl_xor(acc[j], 16);
            acc[j] += __shfl_xor(acc[j], 32);
        }
        if (e == 0) {
            uint4 o;
            o.x = (unsigned)f2bf(acc[0]) | ((unsigned)f2bf(acc[1]) << 16);
            o.y = (unsigned)f2bf(acc[2]) | ((unsigned)f2bf(acc[3]) << 16);
            o.z = (unsigned)f2bf(acc[4]) | ((unsigned)f2bf(acc[5]) << 16);
            o.w = (unsigned)f2bf(acc[6]) | ((unsigned)f2bf(acc[7]) << 16);
            *(uint4*)&aggs[d * DD + (l ^ (d & 15)) * 8] = o;   // swizzled chunk
        }
    }
    __syncthreads();

    // ---- phase B: gnn MFMA; wave w -> rows (w&3)*16, cf half (w>>2)*4 ----
    const int hl = lane & 15, kg = lane >> 4;
    const int rw = (w & 3) * 16;
    const int cfb = (w >> 2) * 4;
    U4B a[4];
#pragma unroll
    for (int ks = 0; ks < 4; ++ks)
        a[ks].u = *(const uint4*)&aggs[(rw + hl) * DD + ((ks * 4 + kg) ^ hl) * 8];

    f32x4 acc[4];
#pragma unroll
    for (int j = 0; j < 4; ++j) acc[j] = (f32x4)0.f;

#pragma unroll
    for (int ks = 0; ks < 4; ++ks) {
        const ushort_t* bp = &wtF[(ks * 8 + cfb) * 512 + lane * 8];
#pragma unroll
        for (int cf = 0; cf < 4; ++cf) {
            bf16x8 bfr = *(const bf16x8*)&bp[cf * 512];
            acc[cf] = __builtin_amdgcn_mfma_f32_16x16x32_bf16(a[ks].b, bfr, acc[cf], 0, 0, 0);
        }
    }

#pragma unroll
    for (int j = 0; j < 4; ++j) {
        int lr = rw + kg * 4 + j;
        int grow = b * 64 + lr;
        if (grow < NN) {
            float s = 1.f / fmaxf((float)hist[lr], 1.f);
#pragma unroll
            for (int cf = 0; cf < 4; ++cf) {
                int gcol = (cfb + cf) * 16 + hl;
                float nv = bf2f((unsigned)news[(long long)grow * DD + gcol]);
                xxb[(long long)grow * DD + gcol] = f2bf(nv + acc[cf][j] * s);
            }
        }
    }
}

// ---------------- fused user vector + scores (bf16 xx gathers) --------------
__global__ __launch_bounds__(128) void k_user(const int* __restrict__ hist,
                                              const int* __restrict__ cand,
                                              const ushort_t* __restrict__ xxb,
                                              float* __restrict__ out) {
    __shared__ float part[2][128];
    __shared__ float cnts[2];
    __shared__ float uvs[128];
    const int b = blockIdx.x, t = threadIdx.x;
    const int w = t >> 6, lane = t & 63;

    float s0 = 0.f, s1 = 0.f, cnt = 0.f;
    for (int h = w; h < HL; h += 2) {
        int id = hist[b * HL + h];
        if (id != 0) {
            unsigned v = *(const unsigned*)&xxb[(long long)id * DD + lane * 2];
            s0 += bf2f(v & 0xFFFFu);
            s1 += bf2f(v >> 16);
            cnt += 1.f;
        }
    }
    part[w][lane * 2]     = s0;
    part[w][lane * 2 + 1] = s1;
    if (lane == 0) cnts[w] = cnt;
    __syncthreads();

    float inv = 1.f / fmaxf(cnts[0] + cnts[1], 1e-9f);
    uvs[t] = (part[0][t] + part[1][t]) * inv;
    __syncthreads();

    float2 uvp = *(const float2*)&uvs[lane * 2];
    for (int c = w; c < CL; c += 2) {
        int id = cand[b * CL + c];
        unsigned v = *(const unsigned*)&xxb[(long long)id * DD + lane * 2];
        float p = uvp.x * bf2f(v & 0xFFFFu) + uvp.y * bf2f(v >> 16);
#pragma unroll
        for (int off = 32; off >= 1; off >>= 1) p += __shfl_xor(p, off);
        if (lane == 0) out[b * CL + c] = p;
    }
}

extern "C" void kernel_launch(void* const* d_in, const int* in_sizes, int n_in,
                              void* d_out, int out_size, void* d_ws, size_t ws_size,
                              hipStream_t stream) {
    const float* x    = (const float*)d_in[0];
    // d_in[1] = n_id == arange(N) -> identity scatter, unused
    const int*   ei   = (const int*)d_in[2];
    const int*   hist = (const int*)d_in[3];
    const int*   cand = (const int*)d_in[4];
    const float* Wenc = (const float*)d_in[5];
    const float* Wgnn = (const float*)d_in[6];
    float* out = (float*)d_out;

    ushort_t* news_bf = (ushort_t*)d_ws;                   // [NN*DD] bf16
    ushort_t* xx_bf   = news_bf + (size_t)NN * DD;         // [NN*DD] bf16
    ushort_t* wt_enc  = xx_bf + (size_t)NN * DD;           // [WTE_N]
    ushort_t* wt_gnn  = wt_enc + WTE_N;                    // [WTG_N]
    uchar_t*  news_f8 = (uchar_t*)(wt_gnn + WTG_N);        // [NN*DD] fp8
    unsigned* gcur    = (unsigned*)(news_f8 + (size_t)NN * DD); // [NBUCK]
    unsigned* pairs   = gcur + NBUCK;                      // [NBUCK*SLOT]

    hipMemsetAsync(gcur, 0, NBUCK * sizeof(unsigned), stream);

    k_wprep<<<PREPB, 256, 0, stream>>>(Wenc, Wgnn, wt_enc, wt_gnn);
    k_encpart<<<PBLK + ENCB, 256, 0, stream>>>(x, wt_enc, ei, gcur, pairs,
                                               news_bf, news_f8);
    k_baggnn<<<NBUCK, 512, 0, stream>>>(gcur, pairs, news_f8, news_bf, wt_gnn, xx_bf);
    k_user<<<NB, 128, 0, stream>>>(hist, cand, xx_bf, out);
}